// Round 10
// baseline (30.088 us; speedup 1.0000x reference)
//
#include <hip/hip_runtime.h>
#include <math.h>

#define NH 16
#define LCACHE 4096

typedef __attribute__((ext_vector_type(8))) short short8;
typedef __attribute__((ext_vector_type(8))) unsigned short ushort8;
typedef __attribute__((ext_vector_type(4))) float f32x4;

__device__ __forceinline__ unsigned short f2bf(float f) {
    unsigned int u = __float_as_uint(f);
    u = (u + 0x7fffu + ((u >> 16) & 1u)) >> 16;   // RNE
    return (unsigned short)u;
}

// ---------------------------------------------------------------------------
// K1 pack-only: 576 blocks x 256 thr.
//  [0,512):   wpack — unit (isP, nt, kt): w_attn[:, :1024] -> wq frags /
//             w_proj -> wp frags, via LDS transpose (coalesced 256B reads).
//  [512,576): xpack — x -> xp A-frags.
// Fragment-linear layout (1 KiB/frag): A f=(mt*16+kt)*4+kb*2+mb,
// B g=(nt*16+kt)*8+kb*4+nb; slot: lane l=(ke>>3)*16+r, j=ke&7.
// ---------------------------------------------------------------------------
__global__ __launch_bounds__(256)
void pack_kernel(const float* __restrict__ x, const float* __restrict__ w_attn,
                 const float* __restrict__ w_proj,
                 ushort* __restrict__ xp, ushort* __restrict__ wq,
                 ushort* __restrict__ wp)
{
    __shared__ float Wt[64][65];
    const int bid = blockIdx.x, tid = threadIdx.x;
    const int w = tid >> 6, l = tid & 63;

    if (bid < 512) {
        const int isP = (bid >= 256);
        const int g2  = bid & 255;
        const int ntw = g2 >> 4, ktw = g2 & 15;
        const float* W = isP ? w_proj : w_attn;
        const int ldw  = isP ? 1024 : 3072;
        ushort* D      = isP ? wp : wq;
#pragma unroll
        for (int rep = 0; rep < 16; ++rep) {
            int lin = rep * 256 + tid;
            int kr = lin >> 6, nn = lin & 63;
            Wt[kr][nn] = W[(size_t)(ktw * 64 + kr) * ldw + ntw * 64 + nn];
        }
        __syncthreads();
        int r = l & 15, kg8 = l >> 4;
#pragma unroll
        for (int e = 0; e < 2; ++e) {
            int bi = w + e * 4;
            int kb = bi >> 2, nb = bi & 3;
            ushort8 o;
#pragma unroll
            for (int j = 0; j < 8; ++j)
                o[j] = f2bf(Wt[kb * 32 + kg8 * 8 + j][nb * 16 + r]);
            size_t f_lin = (size_t)(ntw * 16 + ktw) * 8 + bi;
            *(ushort8*)(D + f_lin * 512 + l * 8) = o;
        }
        return;
    }

    // ---- xpack ----
    {
        int bid2 = bid - 512;                     // 0..63
        int r = l & 15, kg8 = l >> 4;
#pragma unroll
        for (int i = 0; i < 4; ++i) {
            int f = bid2 * 16 + w * 4 + i;        // 0..1023
            int mt = f >> 6, kt = (f >> 2) & 15, fi = f & 3;
            int kb = fi >> 1, mb = fi & 1;
            int m  = mt * 32 + mb * 16 + r;
            int k0 = kt * 64 + kb * 32 + kg8 * 8;
            const float* s = x + (size_t)m * 1024 + k0;
            ushort8 o;
#pragma unroll
            for (int j = 0; j < 8; ++j) o[j] = f2bf(s[j]);
            *(ushort8*)(xp + (size_t)f * 512 + l * 8) = o;
        }
    }
}

// ---------------------------------------------------------------------------
// K2 fused, per (b,h,half), 256 blocks x 512 thr, wave-specialized:
//   waves 0-3: reg-direct q-GEMM (wave owns nb=w, both mb, FULL K=1024;
//              no split-K reduce) -> qs (+bias, softmax scale)
//   waves 4-7: compress conv(s4,k4)+LN for this block's own key rows
//              (half0: 32, half1: 64, K and V) -> scatter into LDS as
//              bf16 MFMA frags (ck: [m=key,k=d]; cv^T: [m=d,k=key])
//   barrier -> MFMA attention (S^T = mfma(ck,q), in-reg softmax, P_lds
//   XOR-swizzled, O^T = mfma(cv^T,P)) -> yp frag scatter.
// ---------------------------------------------------------------------------
__global__ __launch_bounds__(512, 2)
void attn_kernel(const float* __restrict__ cached_k, const float* __restrict__ cached_v,
                 const float* __restrict__ kcw, const float* __restrict__ vcw,
                 const float* __restrict__ lkg, const float* __restrict__ lkb,
                 const float* __restrict__ lvg, const float* __restrict__ lvb,
                 const float* __restrict__ b_attn,
                 const ushort* __restrict__ xp, const ushort* __restrict__ wq,
                 ushort* __restrict__ yp)
{
    __shared__ __align__(16) float qs[32][68];       // 8704 B
    __shared__ __align__(16) ushort P_lds[2048];     // 4096 B
    __shared__ __align__(16) ushort ckf_s[4096];     // 8192 B: 8 frags [mf=key/16][kf=d/32]
    __shared__ __align__(16) ushort cvf_s[4096];     // 8192 B: 8 frags [mf=d/16][kf=key/32]

    const int bid = blockIdx.x;
    const int h    = ((bid & 7) << 1) | ((bid >> 3) & 1);   // same h (and both halves) -> same XCD
    const int rem  = bid >> 4;
    const int b    = rem >> 1;
    const int half = rem & 1;
    const int mtA  = b * 2 + half;

    const int tid = threadIdx.x;
    const int w = tid >> 6, l = tid & 63;
    const int c = l & 15, rg = l >> 4;
    const int g = w & 1, dup = w >> 1;

    // zero frag LDS (guards half0's unused key rows against NaN garbage)
    {
        ushort8 z = {0,0,0,0,0,0,0,0};
        ((ushort8*)ckf_s)[tid] = z;
        ((ushort8*)cvf_s)[tid] = z;
    }
    __syncthreads();

    if (w >= 4) {
        // ================= compress waves =================
        const int cw = w - 4;
        const int NR = half ? 64 : 32;               // key rows needed (per tensor)
        const float* Kb = cached_k + (size_t)(b * NH + h) * (LCACHE * 64);
        const float* Vb = cached_v + (size_t)(b * NH + h) * (LCACHE * 64);
        float4 wk = *(const float4*)(kcw + l * 4);
        float4 wv = *(const float4*)(vcw + l * 4);
        float gk = lkg[l], bk = lkb[l], gv = lvg[l], bv = lvb[l];

        const int iters = (2 * NR) / 4;              // rows per wave
        for (int it = 0; it < iters; it += 4) {      // batch 4 rows (8-way shfl ILP)
            float tap[4][4]; int isKv[4], lcv[4];
#pragma unroll
            for (int q = 0; q < 4; ++q) {
                int t = cw + (it + q) * 4;           // 0..2NR-1, stride-4 across waves
                isKv[q] = (t < NR);
                int lc = isKv[q] ? t : t - NR;
                lcv[q] = lc;
                const float* p = (isKv[q] ? Kb : Vb) + (size_t)lc * 256 + l;
                tap[q][0] = p[0]; tap[q][1] = p[64]; tap[q][2] = p[128]; tap[q][3] = p[192];
            }
            float av[4], s1[4], s2[4];
#pragma unroll
            for (int q = 0; q < 4; ++q) {
                float4 cwv = isKv[q] ? wk : wv;
                float a = tap[q][0] * cwv.x;
                a = fmaf(tap[q][1], cwv.y, a);
                a = fmaf(tap[q][2], cwv.z, a);
                a = fmaf(tap[q][3], cwv.w, a);
                av[q] = a; s1[q] = a; s2[q] = a * a;
            }
#pragma unroll
            for (int o = 32; o; o >>= 1) {
#pragma unroll
                for (int q = 0; q < 4; ++q) {
                    s1[q] += __shfl_xor(s1[q], o);
                    s2[q] += __shfl_xor(s2[q], o);
                }
            }
#pragma unroll
            for (int q = 0; q < 4; ++q) {
                float mu  = s1[q] * 0.015625f;
                float var = s2[q] * 0.015625f - mu * mu;
                float gg = isKv[q] ? gk : gv, bb2 = isKv[q] ? bk : bv;
                float outv = (av[q] - mu) * rsqrtf(var + 1e-5f) * gg + bb2;
                unsigned short bf = f2bf(outv);
                int key = lcv[q], d = l;
                if (isKv[q]) {   // ck frag: (m=key, k=d)
                    int off = ((key >> 4) * 2 + (d >> 5)) * 512
                            + ((d >> 3) & 3) * 128 + (key & 15) * 8 + (d & 7);
                    ckf_s[off] = bf;
                } else {         // cv^T frag: (m=d, k=key)
                    int off = ((d >> 4) * 2 + (key >> 5)) * 512
                            + ((key >> 3) & 3) * 128 + (d & 15) * 8 + (key & 7);
                    cvf_s[off] = bf;
                }
            }
        }
    } else {
        // ================= q-GEMM waves =================
        const ushort* ab = xp + (size_t)mtA * 32768;
        const ushort* bb = wq + (size_t)h * 65536;
        f32x4 acc0 = {0.f,0.f,0.f,0.f}, acc1 = {0.f,0.f,0.f,0.f};
#pragma unroll
        for (int kt = 0; kt < 16; ++kt) {
            const ushort* A = ab + kt * 2048;
            const ushort* B = bb + kt * 4096;
            short8 a00 = *(const short8*)(A + l * 8);                  // kb0 mb0
            short8 a01 = *(const short8*)(A + 512 + l * 8);            // kb0 mb1
            short8 a10 = *(const short8*)(A + 1024 + l * 8);           // kb1 mb0
            short8 a11 = *(const short8*)(A + 1536 + l * 8);           // kb1 mb1
            short8 b0  = *(const short8*)(B + (size_t)w * 512 + l * 8);        // kb0
            short8 b1  = *(const short8*)(B + (size_t)(4 + w) * 512 + l * 8);  // kb1
            acc0 = __builtin_amdgcn_mfma_f32_16x16x32_bf16(a00, b0, acc0, 0, 0, 0);
            acc1 = __builtin_amdgcn_mfma_f32_16x16x32_bf16(a01, b0, acc1, 0, 0, 0);
            acc0 = __builtin_amdgcn_mfma_f32_16x16x32_bf16(a10, b1, acc0, 0, 0, 0);
            acc1 = __builtin_amdgcn_mfma_f32_16x16x32_bf16(a11, b1, acc1, 0, 0, 0);
        }
        // qs write with bias + softmax scale (C/D: row = rg*4+rr, col = c)
        const int n = w * 16 + c;
        float bv2 = b_attn[h * 64 + n];
#pragma unroll
        for (int mb = 0; mb < 2; ++mb) {
            f32x4 acc = mb ? acc1 : acc0;
#pragma unroll
            for (int rr = 0; rr < 4; ++rr)
                qs[mb * 16 + rg * 4 + rr][n] = (acc[rr] + bv2) * 0.125f;
        }
    }
    __syncthreads();

    // ===== MFMA attention (all 8 waves) =====
    short8 akf[4][2];
#pragma unroll
    for (int mf = 0; mf < 4; ++mf)
#pragma unroll
        for (int kf = 0; kf < 2; ++kf)
            akf[mf][kf] = *(const short8*)&ckf_s[(mf * 2 + kf) * 512 + l * 8];
    short8 avf[2];
#pragma unroll
    for (int kf = 0; kf < 2; ++kf)
        avf[kf] = *(const short8*)&cvf_s[(dup * 2 + kf) * 512 + l * 8];

    short8 qb[2];
#pragma unroll
    for (int kf = 0; kf < 2; ++kf) {
        int row = 16 * g + c;
        int d0  = 32 * kf + 8 * rg;
        float4 v0 = *(const float4*)&qs[row][d0];
        float4 v1 = *(const float4*)&qs[row][d0 + 4];
        ushort8 t;
        t[0] = f2bf(v0.x); t[1] = f2bf(v0.y); t[2] = f2bf(v0.z); t[3] = f2bf(v0.w);
        t[4] = f2bf(v1.x); t[5] = f2bf(v1.y); t[6] = f2bf(v1.z); t[7] = f2bf(v1.w);
        qb[kf] = (short8)t;
    }

    f32x4 sacc[4];
#pragma unroll
    for (int mf = 0; mf < 4; ++mf) { sacc[mf][0]=0.f; sacc[mf][1]=0.f; sacc[mf][2]=0.f; sacc[mf][3]=0.f; }
#pragma unroll
    for (int mf = 0; mf < 4; ++mf) {
        sacc[mf] = __builtin_amdgcn_mfma_f32_16x16x32_bf16(akf[mf][0], qb[0], sacc[mf], 0, 0, 0);
        sacc[mf] = __builtin_amdgcn_mfma_f32_16x16x32_bf16(akf[mf][1], qb[1], sacc[mf], 0, 0, 0);
    }

    // softmax: lane holds 16 key-scores for query gq
    const int gq = half * 32 + 16 * g + c;
    float pv[4][4];
    float mx = -3.0e38f;
#pragma unroll
    for (int mf = 0; mf < 4; ++mf)
#pragma unroll
        for (int rr = 0; rr < 4; ++rr) {
            int kidx = 16 * mf + 4 * rg + rr;
            float sc = (kidx <= gq) ? sacc[mf][rr] : -3.0e38f;
            pv[mf][rr] = sc;
            mx = fmaxf(mx, sc);
        }
    mx = fmaxf(mx, __shfl_xor(mx, 16));
    mx = fmaxf(mx, __shfl_xor(mx, 32));
    float sum = 0.f;
#pragma unroll
    for (int mf = 0; mf < 4; ++mf)
#pragma unroll
        for (int rr = 0; rr < 4; ++rr) {
            int kidx = 16 * mf + 4 * rg + rr;
            float e = (kidx <= gq) ? __expf(pv[mf][rr] - mx) : 0.f;
            pv[mf][rr] = e;
            sum += e;
        }
    sum += __shfl_xor(sum, 16);
    sum += __shfl_xor(sum, 32);
    float inv = 1.0f / sum;

    if (dup == 0) {
        int q = 16 * g + c;
        int swz = (q & 7) << 3;
#pragma unroll
        for (int mf = 0; mf < 4; ++mf)
#pragma unroll
            for (int rr = 0; rr < 4; ++rr) {
                int kidx = 16 * mf + 4 * rg + rr;
                P_lds[q * 64 + (kidx ^ swz)] = f2bf(pv[mf][rr] * inv);
            }
    }
    __syncthreads();

    // PV: O^T = mfma(cv^T, P)
    short8 pb[2];
#pragma unroll
    for (int kf = 0; kf < 2; ++kf) {
        int q = 16 * g + c;
        int key0 = 32 * kf + 8 * rg;
        pb[kf] = *(const short8*)&P_lds[q * 64 + (key0 ^ ((q & 7) << 3))];
    }
    f32x4 oacc = {0.f, 0.f, 0.f, 0.f};
    oacc = __builtin_amdgcn_mfma_f32_16x16x32_bf16(avf[0], pb[0], oacc, 0, 0, 0);
    oacc = __builtin_amdgcn_mfma_f32_16x16x32_bf16(avf[1], pb[1], oacc, 0, 0, 0);

    // yp scatter: row i = 16g + c, col d = 16*dup + 4*rg + rr (within head h)
#pragma unroll
    for (int rr = 0; rr < 4; ++rr) {
        int d  = 16 * dup + 4 * rg + rr;
        int kb = d >> 5, ke = d & 31;
        int l2 = ((ke >> 3) << 4) | c;
        int j2 = ke & 7;
        size_t off = (size_t)mtA * 32768 + (size_t)h * 2048
                   + (size_t)(kb * 2 + g) * 512 + (size_t)l2 * 8 + j2;
        yp[off] = f2bf(oacc[rr]);
    }
}

// ---------------------------------------------------------------------------
// K3: out = y @ w_proj + b_proj.  Reg-direct (barrier-free), split-K over
// 8 waves (kg x nb=w4), LDS reduce + bias.  XCD-swizzled nt.
// ---------------------------------------------------------------------------
__global__ __launch_bounds__(512, 2)
void gemm2_kernel(const ushort* __restrict__ Ap, const ushort* __restrict__ Bp,
                  const float* __restrict__ bias, float* __restrict__ C)
{
    __shared__ float red[32][68];

    const int bid = blockIdx.x;
    const int nt = ((bid & 7) << 1) | ((bid >> 3) & 1);
    const int mt = bid >> 4;
    const int tid = threadIdx.x;
    const int w = tid >> 6, l = tid & 63;
    const int kg = w >> 2, w4 = w & 3;
    const int c = l & 15, rg = l >> 4;

    const ushort* ab = Ap + (size_t)mt * 32768;
    const ushort* bb = Bp + (size_t)nt * 65536;
    f32x4 acc0 = {0.f,0.f,0.f,0.f}, acc1 = {0.f,0.f,0.f,0.f};
#pragma unroll
    for (int s = 0; s < 8; ++s) {
        const int kt = kg * 8 + s;
        const ushort* A = ab + kt * 2048;
        const ushort* B = bb + kt * 4096;
        short8 a00 = *(const short8*)(A + l * 8);
        short8 a01 = *(const short8*)(A + 512 + l * 8);
        short8 a10 = *(const short8*)(A + 1024 + l * 8);
        short8 a11 = *(const short8*)(A + 1536 + l * 8);
        short8 b0  = *(const short8*)(B + (size_t)w4 * 512 + l * 8);
        short8 b1  = *(const short8*)(B + (size_t)(4 + w4) * 512 + l * 8);
        acc0 = __builtin_amdgcn_mfma_f32_16x16x32_bf16(a00, b0, acc0, 0, 0, 0);
        acc1 = __builtin_amdgcn_mfma_f32_16x16x32_bf16(a01, b0, acc1, 0, 0, 0);
        acc0 = __builtin_amdgcn_mfma_f32_16x16x32_bf16(a10, b1, acc0, 0, 0, 0);
        acc1 = __builtin_amdgcn_mfma_f32_16x16x32_bf16(a11, b1, acc1, 0, 0, 0);
    }

    const int nl = w4 * 16 + c;
    if (kg == 0) {
#pragma unroll
        for (int mb = 0; mb < 2; ++mb) {
            f32x4 acc = mb ? acc1 : acc0;
#pragma unroll
            for (int rr = 0; rr < 4; ++rr)
                red[mb * 16 + rg * 4 + rr][nl] = acc[rr];
        }
    }
    __syncthreads();
    if (kg == 1) {
        float bv = bias[nt * 64 + nl];
#pragma unroll
        for (int mb = 0; mb < 2; ++mb) {
            f32x4 acc = mb ? acc1 : acc0;
#pragma unroll
            for (int rr = 0; rr < 4; ++rr) {
                int m = mb * 16 + rg * 4 + rr;
                C[(size_t)(mt * 32 + m) * 1024 + nt * 64 + nl] =
                    red[m][nl] + acc[rr] + bv;
            }
        }
    }
}

// ---------------------------------------------------------------------------
extern "C" void kernel_launch(void* const* d_in, const int* in_sizes, int n_in,
                              void* d_out, int out_size, void* d_ws, size_t ws_size,
                              hipStream_t stream)
{
    const float* x        = (const float*)d_in[0];
    const float* cached_k = (const float*)d_in[1];
    const float* cached_v = (const float*)d_in[2];
    const float* w_attn   = (const float*)d_in[3];
    const float* b_attn   = (const float*)d_in[4];
    const float* w_proj   = (const float*)d_in[5];
    const float* b_proj   = (const float*)d_in[6];
    const float* k_conv   = (const float*)d_in[7];
    const float* v_conv   = (const float*)d_in[8];
    const float* ln_k_g   = (const float*)d_in[9];
    const float* ln_k_b   = (const float*)d_in[10];
    const float* ln_v_g   = (const float*)d_in[11];
    const float* ln_v_b   = (const float*)d_in[12];

    ushort* xp = (ushort*)d_ws;            // 524288 u16
    ushort* wq = xp + 524288;              // 1048576 u16
    ushort* wp = wq + 1048576;             // 1048576 u16
    ushort* yp = wp + 1048576;             // 524288 u16
    float* out = (float*)d_out;

    pack_kernel<<<576, 256, 0, stream>>>(x, w_attn, w_proj, xp, wq, wp);
    attn_kernel<<<256, 512, 0, stream>>>(cached_k, cached_v, k_conv, v_conv,
                                         ln_k_g, ln_k_b, ln_v_g, ln_v_b,
                                         b_attn, xp, wq, yp);
    gemm2_kernel<<<256, 512, 0, stream>>>(yp, wp, b_proj, out);
}

// Round 11
// 25.835 us; speedup vs baseline: 1.1646x; 1.1646x over previous
//
#include <hip/hip_runtime.h>
#include <hip/hip_bf16.h>
#include <math.h>

#define NH 16
#define LCACHE 4096

typedef __attribute__((ext_vector_type(8))) short short8;
typedef __attribute__((ext_vector_type(8))) unsigned short ushort8;
typedef __attribute__((ext_vector_type(4))) float f32x4;

__device__ __forceinline__ unsigned short f2bf(float f) {
    __hip_bfloat16 b = __float2bfloat16(f);   // RNE, compiler emits v_cvt_pk pairs
    unsigned short u;
    __builtin_memcpy(&u, &b, 2);
    return u;
}

// ---------------------------------------------------------------------------
// K1 prep: 1024 blocks x 256 thr, 4 blocks/CU.  Every block does:
//   compress: unit (bh, T, quarter) -> 16 rows conv(s4,k4)+LN -> bf16 MFMA
//             frags in global (ck: [m=key,k=d]; cv^T: [m=d,k=key]).
//             All 16 taps prefetched; ONE batched 4-row shuffle tree per wave.
//   wpack:    unit (isP, nt, kt, kbHalf) -> 32x64 W tile via LDS transpose ->
//             4 B-frags (wave = nb).
//   xpack:    frag bid on wave (bid&3) -> xp A-frag.
// Fragment-linear layout (1 KiB/frag): A f=(mt*16+kt)*4+kb*2+mb,
// B g=(nt*16+kt)*8+kb*4+nb; slot: lane l=(ke>>3)*16+r, j=ke&7.
// ---------------------------------------------------------------------------
__global__ __launch_bounds__(256, 4)
void prep_kernel(const float* __restrict__ cached_k, const float* __restrict__ cached_v,
                 const float* __restrict__ kcw, const float* __restrict__ vcw,
                 const float* __restrict__ lkg, const float* __restrict__ lkb,
                 const float* __restrict__ lvg, const float* __restrict__ lvb,
                 const float* __restrict__ x, const float* __restrict__ w_attn,
                 const float* __restrict__ w_proj,
                 ushort* __restrict__ ckf, ushort* __restrict__ cvtf,
                 ushort* __restrict__ xp, ushort* __restrict__ wq,
                 ushort* __restrict__ wp)
{
    __shared__ float Wt[32][65];
    const int bid = blockIdx.x, tid = threadIdx.x;
    const int w = tid >> 6, l = tid & 63;

    // ---- compress tap loads FIRST (critical path): 16 rows/block ----
    const int bh = bid >> 3, sub = bid & 7;
    const int T = sub >> 2, quarter = sub & 3;
    const float* S = (T ? cached_v : cached_k) + (size_t)bh * (LCACHE * 64);
    float tap[4][4];
#pragma unroll
    for (int q = 0; q < 4; ++q) {
        int key = quarter * 16 + w * 4 + q;
        const float* p = S + (size_t)key * 256 + l;
        tap[q][0] = p[0]; tap[q][1] = p[64]; tap[q][2] = p[128]; tap[q][3] = p[192];
    }

    // ---- wpack staging loads second: half-tile 32k x 64n ----
    const int isP = bid >> 9;
    const int rem = bid & 511;
    const int ntw = rem >> 5, ktw = (rem >> 1) & 15, kbh = rem & 1;
    const float* W = isP ? w_proj : w_attn;
    const int ldw  = isP ? 1024 : 3072;
    ushort* D      = isP ? wp : wq;
    float wreg[8];
#pragma unroll
    for (int rep = 0; rep < 8; ++rep) {
        int lin = rep * 256 + tid;               // 0..2047
        int kr = lin >> 6, nn = lin & 63;
        wreg[rep] = W[(size_t)(ktw * 64 + kbh * 32 + kr) * ldw + ntw * 64 + nn];
    }

    // ---- xpack loads (one wave per block, frag = bid) ----
    const int doX = (w == (bid & 3));
    float xr[8];
    if (doX) {
        int f = bid;                              // 0..1023
        int mt = f >> 6, kt = (f >> 2) & 15, fi = f & 3;
        int kb = fi >> 1, mb = fi & 1;
        int r = l & 15, kg8 = l >> 4;
        int m  = mt * 32 + mb * 16 + r;
        int k0 = kt * 64 + kb * 32 + kg8 * 8;
        const float* s = x + (size_t)m * 1024 + k0;
#pragma unroll
        for (int j = 0; j < 8; ++j) xr[j] = s[j];
    }

    // ---- compress compute: one batched 4-row tree ----
    {
        const float* cwp = T ? vcw : kcw;
        float4 w4v = *(const float4*)(cwp + l * 4);
        float g = (T ? lvg : lkg)[l], bb = (T ? lvb : lkb)[l];
        ushort* dstf = (T ? cvtf : ckf) + (size_t)bh * 4096;
        float av[4], s1[4], s2[4];
#pragma unroll
        for (int q = 0; q < 4; ++q) {
            float a = tap[q][0] * w4v.x;
            a = fmaf(tap[q][1], w4v.y, a);
            a = fmaf(tap[q][2], w4v.z, a);
            a = fmaf(tap[q][3], w4v.w, a);
            av[q] = a; s1[q] = a; s2[q] = a * a;
        }
#pragma unroll
        for (int o = 32; o; o >>= 1) {
#pragma unroll
            for (int q = 0; q < 4; ++q) {
                s1[q] += __shfl_xor(s1[q], o);
                s2[q] += __shfl_xor(s2[q], o);
            }
        }
#pragma unroll
        for (int q = 0; q < 4; ++q) {
            int key = quarter * 16 + w * 4 + q;
            float mu  = s1[q] * 0.015625f;
            float var = s2[q] * 0.015625f - mu * mu;
            float outv = (av[q] - mu) * rsqrtf(var + 1e-5f) * g + bb;
            unsigned short bf = f2bf(outv);
            const int d = l;
            int off;
            if (T) // cv^T frag: (m=d, k=key)
                off = ((d >> 4) * 2 + (key >> 5)) * 512
                    + ((key >> 3) & 3) * 128 + (d & 15) * 8 + (key & 7);
            else   // ck frag: (m=key, k=d)
                off = ((key >> 4) * 2 + (d >> 5)) * 512
                    + ((d >> 3) & 3) * 128 + (key & 15) * 8 + (d & 7);
            dstf[off] = bf;
        }
    }

    // ---- wpack: regs -> LDS transpose -> emit 4 frags (wave = nb) ----
    {
#pragma unroll
        for (int rep = 0; rep < 8; ++rep) {
            int lin = rep * 256 + tid;
            Wt[lin >> 6][lin & 63] = wreg[rep];
        }
        __syncthreads();
        int r = l & 15, kg8 = l >> 4;
        ushort8 o;
#pragma unroll
        for (int j = 0; j < 8; ++j)
            o[j] = f2bf(Wt[kg8 * 8 + j][w * 16 + r]);
        size_t f_lin = (size_t)(ntw * 16 + ktw) * 8 + kbh * 4 + w;
        *(ushort8*)(D + f_lin * 512 + l * 8) = o;
    }

    // ---- xpack emit ----
    if (doX) {
        ushort8 o;
#pragma unroll
        for (int j = 0; j < 8; ++j) o[j] = f2bf(xr[j]);
        *(ushort8*)(xp + (size_t)bid * 512 + l * 8) = o;
    }
}

// ---------------------------------------------------------------------------
// K2 (= round-9 proven version): per (b,h,half).  Reg-direct q-GEMM
// (barrier-free; wave = kg x w4, full unroll) | split-K LDS reduce | MFMA
// attention (S^T = mfma(ck,q), in-reg softmax, P_lds XOR-swizzled,
// O^T = mfma(cv^T,P)) | yp frag scatter.  ck/cv frag loads hoisted to top.
// ---------------------------------------------------------------------------
__global__ __launch_bounds__(512, 2)
void attn_kernel(const ushort* __restrict__ ckf, const ushort* __restrict__ cvtf,
                 const float* __restrict__ b_attn,
                 const ushort* __restrict__ xp, const ushort* __restrict__ wq,
                 ushort* __restrict__ yp)
{
    __shared__ __align__(16) float qs[32][68];
    __shared__ __align__(16) ushort P_lds[2048];

    const int bid = blockIdx.x;
    const int h    = ((bid & 7) << 1) | ((bid >> 3) & 1);   // same h -> same XCD
    const int rem  = bid >> 4;
    const int b    = rem >> 1;
    const int half = rem & 1;
    const int mtA  = b * 2 + half;

    const int tid = threadIdx.x;
    const int w = tid >> 6, l = tid & 63;
    const int kg = w >> 2, w4 = w & 3;
    const int c = l & 15, rg = l >> 4;
    const int g = w & 1, dup = w >> 1;

    // hoisted ck/cv fragment loads (land under the q-GEMM)
    const ushort* ckb = ckf + (size_t)(b * NH + h) * 4096;
    const ushort* cvb = cvtf + (size_t)(b * NH + h) * 4096;
    short8 akf[4][2];
#pragma unroll
    for (int mf = 0; mf < 4; ++mf)
#pragma unroll
        for (int kf = 0; kf < 2; ++kf)
            akf[mf][kf] = *(const short8*)(ckb + (mf * 2 + kf) * 512 + l * 8);
    short8 avf[2];
#pragma unroll
    for (int kf = 0; kf < 2; ++kf)
        avf[kf] = *(const short8*)(cvb + (dup * 2 + kf) * 512 + l * 8);

    // reg-direct q-GEMM: wave (kg, w4) owns nb=w4, both mb, K-half kg
    const ushort* ab = xp + (size_t)mtA * 32768;
    const ushort* bb = wq + (size_t)h * 65536;
    f32x4 acc0 = {0.f,0.f,0.f,0.f}, acc1 = {0.f,0.f,0.f,0.f};
#pragma unroll
    for (int s = 0; s < 8; ++s) {
        const int kt = kg * 8 + s;
        const ushort* A = ab + kt * 2048;
        const ushort* B = bb + kt * 4096;
        short8 a00 = *(const short8*)(A + l * 8);
        short8 a01 = *(const short8*)(A + 512 + l * 8);
        short8 a10 = *(const short8*)(A + 1024 + l * 8);
        short8 a11 = *(const short8*)(A + 1536 + l * 8);
        short8 b0  = *(const short8*)(B + (size_t)w4 * 512 + l * 8);
        short8 b1  = *(const short8*)(B + (size_t)(4 + w4) * 512 + l * 8);
        acc0 = __builtin_amdgcn_mfma_f32_16x16x32_bf16(a00, b0, acc0, 0, 0, 0);
        acc1 = __builtin_amdgcn_mfma_f32_16x16x32_bf16(a01, b0, acc1, 0, 0, 0);
        acc0 = __builtin_amdgcn_mfma_f32_16x16x32_bf16(a10, b1, acc0, 0, 0, 0);
        acc1 = __builtin_amdgcn_mfma_f32_16x16x32_bf16(a11, b1, acc1, 0, 0, 0);
    }

    // split-K reduce -> qs (group1 adds bias + softmax scale)
    {
        const int n = w4 * 16 + c;
        if (kg == 0) {
#pragma unroll
            for (int mb = 0; mb < 2; ++mb) {
                f32x4 acc = mb ? acc1 : acc0;
#pragma unroll
                for (int rr = 0; rr < 4; ++rr)
                    qs[mb * 16 + rg * 4 + rr][n] = acc[rr];
            }
        }
        __syncthreads();
        if (kg == 1) {
            float bv = b_attn[h * 64 + n];
#pragma unroll
            for (int mb = 0; mb < 2; ++mb) {
                f32x4 acc = mb ? acc1 : acc0;
#pragma unroll
                for (int rr = 0; rr < 4; ++rr) {
                    int m = mb * 16 + rg * 4 + rr;
                    qs[m][n] = (qs[m][n] + acc[rr] + bv) * 0.125f;
                }
            }
        }
        __syncthreads();
    }

    // ===== MFMA attention =====
    short8 qb[2];
#pragma unroll
    for (int kf = 0; kf < 2; ++kf) {
        int row = 16 * g + c;
        int d0  = 32 * kf + 8 * rg;
        float4 v0 = *(const float4*)&qs[row][d0];
        float4 v1 = *(const float4*)&qs[row][d0 + 4];
        ushort8 t;
        t[0] = f2bf(v0.x); t[1] = f2bf(v0.y); t[2] = f2bf(v0.z); t[3] = f2bf(v0.w);
        t[4] = f2bf(v1.x); t[5] = f2bf(v1.y); t[6] = f2bf(v1.z); t[7] = f2bf(v1.w);
        qb[kf] = (short8)t;
    }

    f32x4 sacc[4];
#pragma unroll
    for (int mf = 0; mf < 4; ++mf) { sacc[mf][0]=0.f; sacc[mf][1]=0.f; sacc[mf][2]=0.f; sacc[mf][3]=0.f; }
#pragma unroll
    for (int mf = 0; mf < 4; ++mf) {
        sacc[mf] = __builtin_amdgcn_mfma_f32_16x16x32_bf16(akf[mf][0], qb[0], sacc[mf], 0, 0, 0);
        sacc[mf] = __builtin_amdgcn_mfma_f32_16x16x32_bf16(akf[mf][1], qb[1], sacc[mf], 0, 0, 0);
    }

    // softmax: lane holds 16 key-scores for query gq
    const int gq = half * 32 + 16 * g + c;
    float pv[4][4];
    float mx = -3.0e38f;
#pragma unroll
    for (int mf = 0; mf < 4; ++mf)
#pragma unroll
        for (int rr = 0; rr < 4; ++rr) {
            int kidx = 16 * mf + 4 * rg + rr;
            float sc = (kidx <= gq) ? sacc[mf][rr] : -3.0e38f;
            pv[mf][rr] = sc;
            mx = fmaxf(mx, sc);
        }
    mx = fmaxf(mx, __shfl_xor(mx, 16));
    mx = fmaxf(mx, __shfl_xor(mx, 32));
    float sum = 0.f;
#pragma unroll
    for (int mf = 0; mf < 4; ++mf)
#pragma unroll
        for (int rr = 0; rr < 4; ++rr) {
            int kidx = 16 * mf + 4 * rg + rr;
            float e = (kidx <= gq) ? __expf(pv[mf][rr] - mx) : 0.f;
            pv[mf][rr] = e;
            sum += e;
        }
    sum += __shfl_xor(sum, 16);
    sum += __shfl_xor(sum, 32);
    float inv = 1.0f / sum;

    if (dup == 0) {
        int q = 16 * g + c;
        int swz = (q & 7) << 3;
#pragma unroll
        for (int mf = 0; mf < 4; ++mf)
#pragma unroll
            for (int rr = 0; rr < 4; ++rr) {
                int kidx = 16 * mf + 4 * rg + rr;
                P_lds[q * 64 + (kidx ^ swz)] = f2bf(pv[mf][rr] * inv);
            }
    }
    __syncthreads();

    // PV: O^T = mfma(cv^T, P)
    short8 pb[2];
#pragma unroll
    for (int kf = 0; kf < 2; ++kf) {
        int q = 16 * g + c;
        int key0 = 32 * kf + 8 * rg;
        pb[kf] = *(const short8*)&P_lds[q * 64 + (key0 ^ ((q & 7) << 3))];
    }
    f32x4 oacc = {0.f, 0.f, 0.f, 0.f};
    oacc = __builtin_amdgcn_mfma_f32_16x16x32_bf16(avf[0], pb[0], oacc, 0, 0, 0);
    oacc = __builtin_amdgcn_mfma_f32_16x16x32_bf16(avf[1], pb[1], oacc, 0, 0, 0);

    // yp scatter: row i = 16g + c, col d = 16*dup + 4*rg + rr (within head h)
#pragma unroll
    for (int rr = 0; rr < 4; ++rr) {
        int d  = 16 * dup + 4 * rg + rr;
        int kb = d >> 5, ke = d & 31;
        int l2 = ((ke >> 3) << 4) | c;
        int j2 = ke & 7;
        size_t off = (size_t)mtA * 32768 + (size_t)h * 2048
                   + (size_t)(kb * 2 + g) * 512 + (size_t)l2 * 8 + j2;
        yp[off] = f2bf(oacc[rr]);
    }
}

// ---------------------------------------------------------------------------
// K3: out = y @ w_proj + b_proj.  512 blocks (2/CU, 16 waves/CU): block =
// (mt, nt2=32-col slice), waves = kg(4, 4 kt each) x nb2(2).  Reg-direct,
// one-sync LDS reduction tree, bijective XCD swizzle on nt2.
// ---------------------------------------------------------------------------
__global__ __launch_bounds__(512, 2)
void gemm2_kernel(const ushort* __restrict__ Ap, const ushort* __restrict__ Bp,
                  const float* __restrict__ bias, float* __restrict__ C)
{
    __shared__ float red[3][2][32][18];

    const int bid = blockIdx.x;                 // 0..511
    const int xcd = bid & 7, idx = bid >> 3;    // idx 0..63
    const int nt2 = xcd * 4 + (idx & 3);        // 0..31: same wp slice -> same XCD
    const int mt  = idx >> 2;                   // 0..15
    const int nt  = nt2 >> 1;
    const int tid = threadIdx.x;
    const int w = tid >> 6, l = tid & 63;
    const int kg = w >> 1, nb2 = w & 1;
    const int nb = (nt2 & 1) * 2 + nb2;
    const int c = l & 15, rg = l >> 4;

    const ushort* ab = Ap + (size_t)mt * 32768;
    const ushort* bb = Bp + (size_t)nt * 65536;
    f32x4 acc0 = {0.f,0.f,0.f,0.f}, acc1 = {0.f,0.f,0.f,0.f};
#pragma unroll
    for (int s = 0; s < 4; ++s) {
        const int kt = kg * 4 + s;
        const ushort* A = ab + kt * 2048;
        const ushort* B = bb + kt * 4096;
        short8 a00 = *(const short8*)(A + l * 8);
        short8 a01 = *(const short8*)(A + 512 + l * 8);
        short8 a10 = *(const short8*)(A + 1024 + l * 8);
        short8 a11 = *(const short8*)(A + 1536 + l * 8);
        short8 b0  = *(const short8*)(B + (size_t)nb * 512 + l * 8);
        short8 b1  = *(const short8*)(B + (size_t)(4 + nb) * 512 + l * 8);
        acc0 = __builtin_amdgcn_mfma_f32_16x16x32_bf16(a00, b0, acc0, 0, 0, 0);
        acc1 = __builtin_amdgcn_mfma_f32_16x16x32_bf16(a01, b0, acc1, 0, 0, 0);
        acc0 = __builtin_amdgcn_mfma_f32_16x16x32_bf16(a10, b1, acc0, 0, 0, 0);
        acc1 = __builtin_amdgcn_mfma_f32_16x16x32_bf16(a11, b1, acc1, 0, 0, 0);
    }

    if (kg > 0) {
#pragma unroll
        for (int mb = 0; mb < 2; ++mb) {
            f32x4 acc = mb ? acc1 : acc0;
#pragma unroll
            for (int rr = 0; rr < 4; ++rr)
                red[kg - 1][nb2][mb * 16 + rg * 4 + rr][c] = acc[rr];
        }
    }
    __syncthreads();
    if (kg == 0) {
        const int n = nt2 * 32 + nb2 * 16 + c;
        float bv = bias[n];
#pragma unroll
        for (int mb = 0; mb < 2; ++mb) {
            f32x4 acc = mb ? acc1 : acc0;
#pragma unroll
            for (int rr = 0; rr < 4; ++rr) {
                int m = mb * 16 + rg * 4 + rr;
                float v = acc[rr] + red[0][nb2][m][c] + red[1][nb2][m][c]
                        + red[2][nb2][m][c] + bv;
                C[(size_t)(mt * 32 + m) * 1024 + n] = v;
            }
        }
    }
}

// ---------------------------------------------------------------------------
extern "C" void kernel_launch(void* const* d_in, const int* in_sizes, int n_in,
                              void* d_out, int out_size, void* d_ws, size_t ws_size,
                              hipStream_t stream)
{
    const float* x        = (const float*)d_in[0];
    const float* cached_k = (const float*)d_in[1];
    const float* cached_v = (const float*)d_in[2];
    const float* w_attn   = (const float*)d_in[3];
    const float* b_attn   = (const float*)d_in[4];
    const float* w_proj   = (const float*)d_in[5];
    const float* b_proj   = (const float*)d_in[6];
    const float* k_conv   = (const float*)d_in[7];
    const float* v_conv   = (const float*)d_in[8];
    const float* ln_k_g   = (const float*)d_in[9];
    const float* ln_k_b   = (const float*)d_in[10];
    const float* ln_v_g   = (const float*)d_in[11];
    const float* ln_v_b   = (const float*)d_in[12];

    ushort* xp   = (ushort*)d_ws;          // 524288 u16
    ushort* wq   = xp + 524288;            // 1048576 u16
    ushort* wp   = wq + 1048576;           // 1048576 u16
    ushort* yp   = wp + 1048576;           // 524288 u16
    ushort* ckf  = yp + 524288;            // 524288 u16
    ushort* cvtf = ckf + 524288;           // 524288 u16
    float* out   = (float*)d_out;

    prep_kernel<<<1024, 256, 0, stream>>>(cached_k, cached_v, k_conv, v_conv,
                                          ln_k_g, ln_k_b, ln_v_g, ln_v_b,
                                          x, w_attn, w_proj, ckf, cvtf, xp, wq, wp);
    attn_kernel<<<256, 512, 0, stream>>>(ckf, cvtf, b_attn, xp, wq, yp);
    gemm2_kernel<<<512, 512, 0, stream>>>(yp, wp, b_proj, out);
}

// Round 12
// 25.788 us; speedup vs baseline: 1.1667x; 1.0018x over previous
//
#include <hip/hip_runtime.h>
#include <hip/hip_bf16.h>
#include <math.h>

#define NH 16
#define LCACHE 4096

typedef __attribute__((ext_vector_type(8))) short short8;
typedef __attribute__((ext_vector_type(8))) unsigned short ushort8;
typedef __attribute__((ext_vector_type(4))) float f32x4;

__device__ __forceinline__ unsigned short f2bf(float f) {
    __hip_bfloat16 b = __float2bfloat16(f);   // RNE
    unsigned short u;
    __builtin_memcpy(&u, &b, 2);
    return u;
}

// ---------------------------------------------------------------------------
// K1 prep (unchanged from round 11): 1024 blocks x 256 thr, 4 blocks/CU.
//   compress: (bh, T, quarter) -> 16 rows conv(s4,k4)+LN -> bf16 MFMA frags
//             (ck: [m=key,k=d]; cv^T: [m=d,k=key]).  Taps prefetched first.
//   wpack:    (isP, nt, kt, kbHalf) -> 32x64 W tile via LDS transpose.
//   xpack:    frag bid on wave (bid&3).
// ---------------------------------------------------------------------------
__global__ __launch_bounds__(256, 4)
void prep_kernel(const float* __restrict__ cached_k, const float* __restrict__ cached_v,
                 const float* __restrict__ kcw, const float* __restrict__ vcw,
                 const float* __restrict__ lkg, const float* __restrict__ lkb,
                 const float* __restrict__ lvg, const float* __restrict__ lvb,
                 const float* __restrict__ x, const float* __restrict__ w_attn,
                 const float* __restrict__ w_proj,
                 ushort* __restrict__ ckf, ushort* __restrict__ cvtf,
                 ushort* __restrict__ xp, ushort* __restrict__ wq,
                 ushort* __restrict__ wp)
{
    __shared__ float Wt[32][65];
    const int bid = blockIdx.x, tid = threadIdx.x;
    const int w = tid >> 6, l = tid & 63;

    // ---- compress tap loads FIRST (critical path): 16 rows/block ----
    const int bh = bid >> 3, sub = bid & 7;
    const int T = sub >> 2, quarter = sub & 3;
    const float* S = (T ? cached_v : cached_k) + (size_t)bh * (LCACHE * 64);
    float tap[4][4];
#pragma unroll
    for (int q = 0; q < 4; ++q) {
        int key = quarter * 16 + w * 4 + q;
        const float* p = S + (size_t)key * 256 + l;
        tap[q][0] = p[0]; tap[q][1] = p[64]; tap[q][2] = p[128]; tap[q][3] = p[192];
    }

    // ---- wpack staging loads second: half-tile 32k x 64n ----
    const int isP = bid >> 9;
    const int rem = bid & 511;
    const int ntw = rem >> 5, ktw = (rem >> 1) & 15, kbh = rem & 1;
    const float* W = isP ? w_proj : w_attn;
    const int ldw  = isP ? 1024 : 3072;
    ushort* D      = isP ? wp : wq;
    float wreg[8];
#pragma unroll
    for (int rep = 0; rep < 8; ++rep) {
        int lin = rep * 256 + tid;
        int kr = lin >> 6, nn = lin & 63;
        wreg[rep] = W[(size_t)(ktw * 64 + kbh * 32 + kr) * ldw + ntw * 64 + nn];
    }

    // ---- xpack loads (one wave per block, frag = bid) ----
    const int doX = (w == (bid & 3));
    float xr[8];
    if (doX) {
        int f = bid;
        int mt = f >> 6, kt = (f >> 2) & 15, fi = f & 3;
        int kb = fi >> 1, mb = fi & 1;
        int r = l & 15, kg8 = l >> 4;
        int m  = mt * 32 + mb * 16 + r;
        int k0 = kt * 64 + kb * 32 + kg8 * 8;
        const float* s = x + (size_t)m * 1024 + k0;
#pragma unroll
        for (int j = 0; j < 8; ++j) xr[j] = s[j];
    }

    // ---- compress compute: one batched 4-row tree ----
    {
        const float* cwp = T ? vcw : kcw;
        float4 w4v = *(const float4*)(cwp + l * 4);
        float g = (T ? lvg : lkg)[l], bb = (T ? lvb : lkb)[l];
        ushort* dstf = (T ? cvtf : ckf) + (size_t)bh * 4096;
        float av[4], s1[4], s2[4];
#pragma unroll
        for (int q = 0; q < 4; ++q) {
            float a = tap[q][0] * w4v.x;
            a = fmaf(tap[q][1], w4v.y, a);
            a = fmaf(tap[q][2], w4v.z, a);
            a = fmaf(tap[q][3], w4v.w, a);
            av[q] = a; s1[q] = a; s2[q] = a * a;
        }
#pragma unroll
        for (int o = 32; o; o >>= 1) {
#pragma unroll
            for (int q = 0; q < 4; ++q) {
                s1[q] += __shfl_xor(s1[q], o);
                s2[q] += __shfl_xor(s2[q], o);
            }
        }
#pragma unroll
        for (int q = 0; q < 4; ++q) {
            int key = quarter * 16 + w * 4 + q;
            float mu  = s1[q] * 0.015625f;
            float var = s2[q] * 0.015625f - mu * mu;
            float outv = (av[q] - mu) * rsqrtf(var + 1e-5f) * g + bb;
            unsigned short bf = f2bf(outv);
            const int d = l;
            int off;
            if (T) // cv^T frag: (m=d, k=key)
                off = ((d >> 4) * 2 + (key >> 5)) * 512
                    + ((key >> 3) & 3) * 128 + (d & 15) * 8 + (key & 7);
            else   // ck frag: (m=key, k=d)
                off = ((key >> 4) * 2 + (d >> 5)) * 512
                    + ((d >> 3) & 3) * 128 + (key & 15) * 8 + (d & 7);
            dstf[off] = bf;
        }
    }

    // ---- wpack: regs -> LDS transpose -> emit 4 frags (wave = nb) ----
    {
#pragma unroll
        for (int rep = 0; rep < 8; ++rep) {
            int lin = rep * 256 + tid;
            Wt[lin >> 6][lin & 63] = wreg[rep];
        }
        __syncthreads();
        int r = l & 15, kg8 = l >> 4;
        ushort8 o;
#pragma unroll
        for (int j = 0; j < 8; ++j)
            o[j] = f2bf(Wt[kg8 * 8 + j][w * 16 + r]);
        size_t f_lin = (size_t)(ntw * 16 + ktw) * 8 + kbh * 4 + w;
        *(ushort8*)(D + f_lin * 512 + l * 8) = o;
    }

    // ---- xpack emit ----
    if (doX) {
        ushort8 o;
#pragma unroll
        for (int j = 0; j < 8; ++j) o[j] = f2bf(xr[j]);
        *(ushort8*)(xp + (size_t)bid * 512 + l * 8) = o;
    }
}

// ---------------------------------------------------------------------------
// K2: 512 blocks x 256 thr (2 blocks/CU).  block = (b, h, query-quarter q2):
// 16 queries.  4 waves:
//   q-GEMM 16x64: wave (kg = w>>1, w2 = w&1) reg-direct, split-K-2, two
//   16-col slices per wave; FP order identical to round 11.
//   QK + softmax + P_lds: ONE wave (w == bid&3; akf loaded only there).
//   PV: wave = d-slice (dup = w).  yp frag scatter.
// ---------------------------------------------------------------------------
__global__ __launch_bounds__(256, 2)
void attn_kernel(const ushort* __restrict__ ckf, const ushort* __restrict__ cvtf,
                 const float* __restrict__ b_attn,
                 const ushort* __restrict__ xp, const ushort* __restrict__ wq,
                 ushort* __restrict__ yp)
{
    __shared__ __align__(16) float qs[16][68];
    __shared__ __align__(16) ushort P_lds[1024];   // 16 q x 64 keys

    const int bid = blockIdx.x;
    const int h   = ((bid & 7) << 1) | ((bid >> 3) & 1);   // same h -> same XCD
    const int rem = bid >> 4;                               // 0..31
    const int b   = rem >> 2;
    const int q2  = rem & 3;                                // query quarter
    const int mtA = b * 2 + (q2 >> 1);
    const int mb  = q2 & 1;

    const int tid = threadIdx.x;
    const int w = tid >> 6, l = tid & 63;
    const int kg = w >> 1, w2 = w & 1;
    const int c = l & 15, rg = l >> 4;
    const int qkw = bid & 3;              // QK wave id (spread across SIMDs)

    // hoisted cv frag loads (all waves; dup = w) + ck (QK wave only)
    const ushort* cvb = cvtf + (size_t)(b * NH + h) * 4096;
    short8 avf[2];
#pragma unroll
    for (int kf = 0; kf < 2; ++kf)
        avf[kf] = *(const short8*)(cvb + (w * 2 + kf) * 512 + l * 8);

    short8 akf[4][2];
    if (w == qkw) {
        const ushort* ckb = ckf + (size_t)(b * NH + h) * 4096;
#pragma unroll
        for (int mf = 0; mf < 4; ++mf)
#pragma unroll
            for (int kf = 0; kf < 2; ++kf)
                akf[mf][kf] = *(const short8*)(ckb + (mf * 2 + kf) * 512 + l * 8);
    }

    // ---- reg-direct q-GEMM 16x64, split-K-2 ----
    const ushort* ab = xp + (size_t)mtA * 32768 + mb * 512;
    const ushort* bb = wq + (size_t)h * 65536 + w2 * 1024;
    f32x4 acc0 = {0.f,0.f,0.f,0.f}, acc1 = {0.f,0.f,0.f,0.f};
#pragma unroll
    for (int s = 0; s < 8; ++s) {
        const int kt = kg * 8 + s;
        const ushort* A = ab + kt * 2048;
        const ushort* B = bb + kt * 4096;
        short8 a0  = *(const short8*)(A + l * 8);            // kb0, mb
        short8 a1  = *(const short8*)(A + 1024 + l * 8);     // kb1, mb
        short8 b00 = *(const short8*)(B + l * 8);            // kb0, nb0
        short8 b01 = *(const short8*)(B + 512 + l * 8);      // kb0, nb1
        short8 b10 = *(const short8*)(B + 2048 + l * 8);     // kb1, nb0
        short8 b11 = *(const short8*)(B + 2560 + l * 8);     // kb1, nb1
        acc0 = __builtin_amdgcn_mfma_f32_16x16x32_bf16(a0, b00, acc0, 0, 0, 0);
        acc1 = __builtin_amdgcn_mfma_f32_16x16x32_bf16(a0, b01, acc1, 0, 0, 0);
        acc0 = __builtin_amdgcn_mfma_f32_16x16x32_bf16(a1, b10, acc0, 0, 0, 0);
        acc1 = __builtin_amdgcn_mfma_f32_16x16x32_bf16(a1, b11, acc1, 0, 0, 0);
    }

    // split-K reduce -> qs (kg1 adds bias + softmax scale)
    {
        const int n0 = w2 * 32 + c;
        if (kg == 0) {
#pragma unroll
            for (int rr = 0; rr < 4; ++rr) {
                qs[rg * 4 + rr][n0]      = acc0[rr];
                qs[rg * 4 + rr][n0 + 16] = acc1[rr];
            }
        }
        __syncthreads();
        if (kg == 1) {
            float bv0 = b_attn[h * 64 + n0];
            float bv1 = b_attn[h * 64 + n0 + 16];
#pragma unroll
            for (int rr = 0; rr < 4; ++rr) {
                int m = rg * 4 + rr;
                qs[m][n0]      = (qs[m][n0]      + acc0[rr] + bv0) * 0.125f;
                qs[m][n0 + 16] = (qs[m][n0 + 16] + acc1[rr] + bv1) * 0.125f;
            }
        }
        __syncthreads();
    }

    // ---- QK + softmax + P (one wave) ----
    if (w == qkw) {
        short8 qb[2];
#pragma unroll
        for (int kf = 0; kf < 2; ++kf) {
            int d0 = 32 * kf + 8 * rg;
            float4 v0 = *(const float4*)&qs[c][d0];
            float4 v1 = *(const float4*)&qs[c][d0 + 4];
            ushort8 t;
            t[0] = f2bf(v0.x); t[1] = f2bf(v0.y); t[2] = f2bf(v0.z); t[3] = f2bf(v0.w);
            t[4] = f2bf(v1.x); t[5] = f2bf(v1.y); t[6] = f2bf(v1.z); t[7] = f2bf(v1.w);
            qb[kf] = (short8)t;
        }

        f32x4 sacc[4];
#pragma unroll
        for (int mf = 0; mf < 4; ++mf) { sacc[mf][0]=0.f; sacc[mf][1]=0.f; sacc[mf][2]=0.f; sacc[mf][3]=0.f; }
#pragma unroll
        for (int mf = 0; mf < 4; ++mf) {
            sacc[mf] = __builtin_amdgcn_mfma_f32_16x16x32_bf16(akf[mf][0], qb[0], sacc[mf], 0, 0, 0);
            sacc[mf] = __builtin_amdgcn_mfma_f32_16x16x32_bf16(akf[mf][1], qb[1], sacc[mf], 0, 0, 0);
        }

        // softmax: lane (c, rg) holds keys {16mf + 4rg + rr} of query gq
        const int gq = q2 * 16 + c;
        float pv[4][4];
        float mx = -3.0e38f;
#pragma unroll
        for (int mf = 0; mf < 4; ++mf)
#pragma unroll
            for (int rr = 0; rr < 4; ++rr) {
                int kidx = 16 * mf + 4 * rg + rr;
                float sc = (kidx <= gq) ? sacc[mf][rr] : -3.0e38f;
                pv[mf][rr] = sc;
                mx = fmaxf(mx, sc);
            }
        mx = fmaxf(mx, __shfl_xor(mx, 16));
        mx = fmaxf(mx, __shfl_xor(mx, 32));
        float sum = 0.f;
#pragma unroll
        for (int mf = 0; mf < 4; ++mf)
#pragma unroll
            for (int rr = 0; rr < 4; ++rr) {
                int kidx = 16 * mf + 4 * rg + rr;
                float e = (kidx <= gq) ? __expf(pv[mf][rr] - mx) : 0.f;
                pv[mf][rr] = e;
                sum += e;
            }
        sum += __shfl_xor(sum, 16);
        sum += __shfl_xor(sum, 32);
        float inv = 1.0f / sum;

        int swz = (c & 7) << 3;
#pragma unroll
        for (int mf = 0; mf < 4; ++mf)
#pragma unroll
            for (int rr = 0; rr < 4; ++rr) {
                int kidx = 16 * mf + 4 * rg + rr;
                P_lds[c * 64 + (kidx ^ swz)] = f2bf(pv[mf][rr] * inv);
            }
    }
    __syncthreads();

    // ---- PV: O^T = mfma(cv^T, P); wave = d-slice ----
    short8 pb[2];
#pragma unroll
    for (int kf = 0; kf < 2; ++kf) {
        int key0 = 32 * kf + 8 * rg;
        pb[kf] = *(const short8*)&P_lds[c * 64 + (key0 ^ ((c & 7) << 3))];
    }
    f32x4 oacc = {0.f, 0.f, 0.f, 0.f};
    oacc = __builtin_amdgcn_mfma_f32_16x16x32_bf16(avf[0], pb[0], oacc, 0, 0, 0);
    oacc = __builtin_amdgcn_mfma_f32_16x16x32_bf16(avf[1], pb[1], oacc, 0, 0, 0);

    // yp scatter: query col c, d = 16w + 4rg + rr
#pragma unroll
    for (int rr = 0; rr < 4; ++rr) {
        int d  = 16 * w + 4 * rg + rr;
        int kb = d >> 5, ke = d & 31;
        int l2 = ((ke >> 3) << 4) | c;
        int j2 = ke & 7;
        size_t off = (size_t)mtA * 32768 + (size_t)h * 2048
                   + (size_t)(kb * 2 + mb) * 512 + (size_t)l2 * 8 + j2;
        yp[off] = f2bf(oacc[rr]);
    }
}

// ---------------------------------------------------------------------------
// K3 (unchanged from round 11): 512 blocks (2/CU): block = (mt, nt2=32-col
// slice), waves = kg(4) x nb2(2).  Reg-direct, one-sync LDS reduction tree.
// ---------------------------------------------------------------------------
__global__ __launch_bounds__(512, 2)
void gemm2_kernel(const ushort* __restrict__ Ap, const ushort* __restrict__ Bp,
                  const float* __restrict__ bias, float* __restrict__ C)
{
    __shared__ float red[3][2][32][18];

    const int bid = blockIdx.x;
    const int xcd = bid & 7, idx = bid >> 3;
    const int nt2 = xcd * 4 + (idx & 3);
    const int mt  = idx >> 2;
    const int nt  = nt2 >> 1;
    const int tid = threadIdx.x;
    const int w = tid >> 6, l = tid & 63;
    const int kg = w >> 1, nb2 = w & 1;
    const int nb = (nt2 & 1) * 2 + nb2;
    const int c = l & 15, rg = l >> 4;

    const ushort* ab = Ap + (size_t)mt * 32768;
    const ushort* bb = Bp + (size_t)nt * 65536;
    f32x4 acc0 = {0.f,0.f,0.f,0.f}, acc1 = {0.f,0.f,0.f,0.f};
#pragma unroll
    for (int s = 0; s < 4; ++s) {
        const int kt = kg * 4 + s;
        const ushort* A = ab + kt * 2048;
        const ushort* B = bb + kt * 4096;
        short8 a00 = *(const short8*)(A + l * 8);
        short8 a01 = *(const short8*)(A + 512 + l * 8);
        short8 a10 = *(const short8*)(A + 1024 + l * 8);
        short8 a11 = *(const short8*)(A + 1536 + l * 8);
        short8 b0  = *(const short8*)(B + (size_t)nb * 512 + l * 8);
        short8 b1  = *(const short8*)(B + (size_t)(4 + nb) * 512 + l * 8);
        acc0 = __builtin_amdgcn_mfma_f32_16x16x32_bf16(a00, b0, acc0, 0, 0, 0);
        acc1 = __builtin_amdgcn_mfma_f32_16x16x32_bf16(a01, b0, acc1, 0, 0, 0);
        acc0 = __builtin_amdgcn_mfma_f32_16x16x32_bf16(a10, b1, acc0, 0, 0, 0);
        acc1 = __builtin_amdgcn_mfma_f32_16x16x32_bf16(a11, b1, acc1, 0, 0, 0);
    }

    if (kg > 0) {
#pragma unroll
        for (int mb = 0; mb < 2; ++mb) {
            f32x4 acc = mb ? acc1 : acc0;
#pragma unroll
            for (int rr = 0; rr < 4; ++rr)
                red[kg - 1][nb2][mb * 16 + rg * 4 + rr][c] = acc[rr];
        }
    }
    __syncthreads();
    if (kg == 0) {
        const int n = nt2 * 32 + nb2 * 16 + c;
        float bv = bias[n];
#pragma unroll
        for (int mb = 0; mb < 2; ++mb) {
            f32x4 acc = mb ? acc1 : acc0;
#pragma unroll
            for (int rr = 0; rr < 4; ++rr) {
                int m = mb * 16 + rg * 4 + rr;
                float v = acc[rr] + red[0][nb2][m][c] + red[1][nb2][m][c]
                        + red[2][nb2][m][c] + bv;
                C[(size_t)(mt * 32 + m) * 1024 + n] = v;
            }
        }
    }
}

// ---------------------------------------------------------------------------
extern "C" void kernel_launch(void* const* d_in, const int* in_sizes, int n_in,
                              void* d_out, int out_size, void* d_ws, size_t ws_size,
                              hipStream_t stream)
{
    const float* x        = (const float*)d_in[0];
    const float* cached_k = (const float*)d_in[1];
    const float* cached_v = (const float*)d_in[2];
    const float* w_attn   = (const float*)d_in[3];
    const float* b_attn   = (const float*)d_in[4];
    const float* w_proj   = (const float*)d_in[5];
    const float* b_proj   = (const float*)d_in[6];
    const float* k_conv   = (const float*)d_in[7];
    const float* v_conv   = (const float*)d_in[8];
    const float* ln_k_g   = (const float*)d_in[9];
    const float* ln_k_b   = (const float*)d_in[10];
    const float* ln_v_g   = (const float*)d_in[11];
    const float* ln_v_b   = (const float*)d_in[12];

    ushort* xp   = (ushort*)d_ws;          // 524288 u16
    ushort* wq   = xp + 524288;            // 1048576 u16
    ushort* wp   = wq + 1048576;           // 1048576 u16
    ushort* yp   = wp + 1048576;           // 524288 u16
    ushort* ckf  = yp + 524288;            // 524288 u16
    ushort* cvtf = ckf + 524288;           // 524288 u16
    float* out   = (float*)d_out;

    prep_kernel<<<1024, 256, 0, stream>>>(cached_k, cached_v, k_conv, v_conv,
                                          ln_k_g, ln_k_b, ln_v_g, ln_v_b,
                                          x, w_attn, w_proj, ckf, cvtf, xp, wq, wp);
    attn_kernel<<<512, 256, 0, stream>>>(ckf, cvtf, b_attn, xp, wq, yp);
    gemm2_kernel<<<512, 512, 0, stream>>>(yp, wp, b_proj, out);
}